// Round 3
// baseline (123.381 us; speedup 1.0000x reference)
//
#include <hip/hip_runtime.h>

#define BB 64
#define KK 16
#define LL 16384
#define CAP 2048

// ---------------------------------------------------------------------------
// Kernel 1: per-batch-row mask statistics.
//   stats[2b]   = 1 / max(sum(mask_b), 1e-12)        (q scale)
//   stats[2b+1] = sum(mask_b^2) / max(sum,1e-12)^2   (= sum q^2)
// ---------------------------------------------------------------------------
__global__ __launch_bounds__(256) void mask_stats_kernel(
    const float* __restrict__ mask, float* __restrict__ stats) {
  int b = blockIdx.x;
  const float* m = mask + (size_t)b * LL;
  int t = threadIdx.x;
  float s = 0.f, sq = 0.f;
#pragma unroll
  for (int j = 0; j < 16; ++j) {
    float4 v = reinterpret_cast<const float4*>(m)[j * 256 + t];
    s  += v.x + v.y + v.z + v.w;
    sq += v.x * v.x + v.y * v.y + v.z * v.z + v.w * v.w;
  }
  for (int off = 32; off; off >>= 1) {
    s  += __shfl_xor(s, off);
    sq += __shfl_xor(sq, off);
  }
  __shared__ float ls[4], lsq[4];
  int wave = t >> 6;
  if ((t & 63) == 0) { ls[wave] = s; lsq[wave] = sq; }
  __syncthreads();
  if (t == 0) {
    float S  = ls[0] + ls[1] + ls[2] + ls[3];
    float SQ = lsq[0] + lsq[1] + lsq[2] + lsq[3];
    float inv = 1.0f / fmaxf(S, 1e-12f);
    stats[2 * b]     = inv;
    stats[2 * b + 1] = SQ * inv * inv;
  }
}

// ---------------------------------------------------------------------------
// Kernel 2: one workgroup per (b,k) row.  TWO-PASS over the row:
//   pass 1: streaming max (no values retained -> low VGPR, loads pipeline)
//   pass 2: re-scan (XCD-L2 warm) compacting candidates {z > zmax-1} to LDS
// Candidates are a superset of the sparsemax support (tau >= zmax-1).
// Fast path: wave 0 bitonic-sorts <=64 candidates in-register and applies
// the reference's exact support test.  Loss = sum p^2 - 2 sum pq + sum q^2.
// ---------------------------------------------------------------------------
__global__ __launch_bounds__(256) void sparsemax_loss_kernel(
    const float* __restrict__ logits, const float* __restrict__ mask,
    const float* __restrict__ stats, float* __restrict__ out) {
  int row = blockIdx.x;        // b*K + k
  int b = row >> 4;            // K == 16
  const float* z = logits + (size_t)row * LL;
  const float* m = mask + (size_t)b * LL;
  const float4* zv = reinterpret_cast<const float4*>(z);
  int t = threadIdx.x;
  int wave = t >> 6, lane = t & 63;

  __shared__ float lds_val[CAP];
  __shared__ int   lds_idx[CAP];
  __shared__ int   lds_n;
  __shared__ float lds_f[4];

  if (t == 0) lds_n = 0;

  // ---- pass 1: streaming max; 4 independent accumulators so all 16
  //      loads stay in flight (no cross-iteration dependence) ----
  float mx0 = -3.0e38f, mx1 = -3.0e38f, mx2 = -3.0e38f, mx3 = -3.0e38f;
#pragma unroll
  for (int j = 0; j < 4; ++j) {
    float4 a = zv[(4 * j + 0) * 256 + t];
    float4 c = zv[(4 * j + 1) * 256 + t];
    float4 d = zv[(4 * j + 2) * 256 + t];
    float4 e = zv[(4 * j + 3) * 256 + t];
    mx0 = fmaxf(mx0, fmaxf(fmaxf(a.x, a.y), fmaxf(a.z, a.w)));
    mx1 = fmaxf(mx1, fmaxf(fmaxf(c.x, c.y), fmaxf(c.z, c.w)));
    mx2 = fmaxf(mx2, fmaxf(fmaxf(d.x, d.y), fmaxf(d.z, d.w)));
    mx3 = fmaxf(mx3, fmaxf(fmaxf(e.x, e.y), fmaxf(e.z, e.w)));
  }
  float vmax = fmaxf(fmaxf(mx0, mx1), fmaxf(mx2, mx3));
  for (int off = 32; off; off >>= 1) vmax = fmaxf(vmax, __shfl_xor(vmax, off));
  if (lane == 0) lds_f[wave] = vmax;
  __syncthreads();
  float zmax = fmaxf(fmaxf(lds_f[0], lds_f[1]), fmaxf(lds_f[2], lds_f[3]));
  float thr = zmax - 1.0f;

  // ---- pass 2: re-scan (L2-warm) + candidate compaction into LDS ----
#pragma unroll
  for (int j = 0; j < 16; ++j) {
    float4 a = zv[j * 256 + t];
    int base = (j * 256 + t) * 4;
    float vv[4] = {a.x, a.y, a.z, a.w};
#pragma unroll
    for (int e = 0; e < 4; ++e) {
      if (vv[e] > thr) {
        int pos = atomicAdd(&lds_n, 1);
        if (pos < CAP) { lds_val[pos] = vv[e]; lds_idx[pos] = base + e; }
      }
    }
  }
  __syncthreads();
  int n = lds_n;
  float inv_s = stats[2 * b];
  float sumq2 = stats[2 * b + 1];
  const float scale = 0.5f / (float)(BB * KK);

  if (n <= 64) {
    // ================= fast path: exact sorted solve on wave 0 ============
    if (wave == 0) {
      float c = (lane < n) ? lds_val[lane] : -3.0e38f;
      // bitonic sort, descending across 64 lanes
#pragma unroll
      for (int size = 2; size <= 64; size <<= 1) {
#pragma unroll
        for (int stride = size >> 1; stride > 0; stride >>= 1) {
          float other = __shfl_xor(c, stride);
          bool dirDesc = ((lane & size) == 0);
          bool takeMax = (dirDesc == ((lane & stride) == 0));
          float mn = fminf(c, other), mxv = fmaxf(c, other);
          c = takeMax ? mxv : mn;
        }
      }
      // inclusive prefix sum of sorted values
      float cum = c;
#pragma unroll
      for (int off = 1; off < 64; off <<= 1) {
        float y = __shfl_up(cum, off);
        if (lane >= off) cum += y;
      }
      // reference support test: 1 + k*z_sorted > cumsum
      bool sup = (lane < n) && (1.0f + (float)(lane + 1) * c > cum);
      unsigned long long bal = __ballot(sup);
      int k = __popcll(bal);              // k >= 1 always (top element)
      float S = sup ? c : 0.f;
      for (int off = 32; off; off >>= 1) S += __shfl_xor(S, off);
      float tau = (S - 1.0f) / (float)k;

      // loss over the (unsorted) candidate list; p == 0 outside it
      float a1 = 0.f, a2 = 0.f;
      if (lane < n) {
        float val = lds_val[lane];
        float p = fmaxf(val - tau, 0.f);
        if (p > 0.f) {
          float q = m[lds_idx[lane]] * inv_s;
          a1 = p * p;
          a2 = p * q;
        }
      }
      for (int off = 32; off; off >>= 1) {
        a1 += __shfl_xor(a1, off);
        a2 += __shfl_xor(a2, off);
      }
      if (lane == 0) atomicAdd(out, (a1 - 2.f * a2 + sumq2) * scale);
    }
  } else if (n <= CAP) {
    // ============ mid path: wave-0 bisection over LDS candidates ==========
    if (wave == 0) {
      int nj = (n + 63) >> 6;
      float lo = thr, hi = zmax;
      for (int it = 0; it < 30; ++it) {
        float mid = 0.5f * (lo + hi);
        float s = 0.f;
        for (int j = 0; j < nj; ++j) {
          int i = j * 64 + lane;
          float cc = (i < n) ? lds_val[i] : -3.0e38f;
          s += fmaxf(cc - mid, 0.f);
        }
        for (int off = 32; off; off >>= 1) s += __shfl_xor(s, off);
        if (s >= 1.0f) lo = mid; else hi = mid;
      }
      float S = 0.f, kc = 0.f;
      for (int j = 0; j < nj; ++j) {
        int i = j * 64 + lane;
        float cc = (i < n) ? lds_val[i] : -3.0e38f;
        if (cc > lo) { S += cc; kc += 1.f; }
      }
      for (int off = 32; off; off >>= 1) {
        S  += __shfl_xor(S, off);
        kc += __shfl_xor(kc, off);
      }
      float tau = (S - 1.0f) / kc;

      float a1 = 0.f, a2 = 0.f;
      for (int j = 0; j < nj; ++j) {
        int i = j * 64 + lane;
        if (i < n) {
          float p = fmaxf(lds_val[i] - tau, 0.f);
          if (p > 0.f) {
            float q = m[lds_idx[i]] * inv_s;
            a1 += p * p;
            a2 += p * q;
          }
        }
      }
      for (int off = 32; off; off >>= 1) {
        a1 += __shfl_xor(a1, off);
        a2 += __shfl_xor(a2, off);
      }
      if (lane == 0) atomicAdd(out, (a1 - 2.f * a2 + sumq2) * scale);
    }
  } else {
    // ===== slow path (unreachable for this data): block bisection over
    //       global memory re-reads; correctness only ======================
    __shared__ float red[4], red2[4];
    float lo = thr, hi = zmax;
    for (int it = 0; it < 30; ++it) {
      float mid = 0.5f * (lo + hi);
      float s = 0.f;
      for (int j = 0; j < 16; ++j) {
        float4 vv = zv[j * 256 + t];
        s += fmaxf(vv.x - mid, 0.f) + fmaxf(vv.y - mid, 0.f) +
             fmaxf(vv.z - mid, 0.f) + fmaxf(vv.w - mid, 0.f);
      }
      for (int off = 32; off; off >>= 1) s += __shfl_xor(s, off);
      __syncthreads();
      if (lane == 0) red[wave] = s;
      __syncthreads();
      float tot = red[0] + red[1] + red[2] + red[3];
      if (tot >= 1.0f) lo = mid; else hi = mid;
    }
    float S = 0.f, kc = 0.f;
    for (int j = 0; j < 16; ++j) {
      float4 vv4 = zv[j * 256 + t];
      float vv[4] = {vv4.x, vv4.y, vv4.z, vv4.w};
      for (int e = 0; e < 4; ++e)
        if (vv[e] > lo) { S += vv[e]; kc += 1.f; }
    }
    for (int off = 32; off; off >>= 1) {
      S  += __shfl_xor(S, off);
      kc += __shfl_xor(kc, off);
    }
    __syncthreads();
    if (lane == 0) { red[wave] = S; red2[wave] = kc; }
    __syncthreads();
    S  = red[0] + red[1] + red[2] + red[3];
    kc = red2[0] + red2[1] + red2[2] + red2[3];
    float tau = (S - 1.0f) / kc;

    float a1 = 0.f, a2 = 0.f;
    for (int j = 0; j < 16; ++j) {
      int base = (j * 256 + t) * 4;
      float4 vv4 = zv[j * 256 + t];
      float vv[4] = {vv4.x, vv4.y, vv4.z, vv4.w};
      for (int e = 0; e < 4; ++e) {
        float p = fmaxf(vv[e] - tau, 0.f);
        if (p > 0.f) {
          float q = m[base + e] * inv_s;
          a1 += p * p;
          a2 += p * q;
        }
      }
    }
    for (int off = 32; off; off >>= 1) {
      a1 += __shfl_xor(a1, off);
      a2 += __shfl_xor(a2, off);
    }
    __syncthreads();
    if (lane == 0) { red[wave] = a1; red2[wave] = a2; }
    __syncthreads();
    if (t == 0) {
      a1 = red[0] + red[1] + red[2] + red[3];
      a2 = red2[0] + red2[1] + red2[2] + red2[3];
      atomicAdd(out, (a1 - 2.f * a2 + sumq2) * scale);
    }
  }
}

extern "C" void kernel_launch(void* const* d_in, const int* in_sizes, int n_in,
                              void* d_out, int out_size, void* d_ws, size_t ws_size,
                              hipStream_t stream) {
  const float* logits = (const float*)d_in[0];  // (B,K,L) fp32
  const float* mask   = (const float*)d_in[1];  // (B,L)   fp32
  float* stats = (float*)d_ws;                  // 64 * 2 floats
  float* out   = (float*)d_out;                 // scalar fp32

  hipMemsetAsync(out, 0, sizeof(float), stream);
  mask_stats_kernel<<<BB, 256, 0, stream>>>(mask, stats);
  sparsemax_loss_kernel<<<BB * KK, 256, 0, stream>>>(logits, mask, stats, out);
}

// Round 4
// 109.324 us; speedup vs baseline: 1.1286x; 1.1286x over previous
//
#include <hip/hip_runtime.h>

#define BB 64
#define KK 16
#define LL 16384
#define CAP 2048

// ---------------------------------------------------------------------------
// Kernel 1: per-batch-row mask statistics.
//   stats[2b]   = 1 / max(sum(mask_b), 1e-12)        (q scale)
//   stats[2b+1] = sum(mask_b^2) / max(sum,1e-12)^2   (= sum q^2)
// ---------------------------------------------------------------------------
__global__ __launch_bounds__(256) void mask_stats_kernel(
    const float* __restrict__ mask, float* __restrict__ stats) {
  int b = blockIdx.x;
  const float* m = mask + (size_t)b * LL;
  int t = threadIdx.x;
  float s = 0.f, sq = 0.f;
#pragma unroll
  for (int j = 0; j < 16; ++j) {
    float4 v = reinterpret_cast<const float4*>(m)[j * 256 + t];
    s  += v.x + v.y + v.z + v.w;
    sq += v.x * v.x + v.y * v.y + v.z * v.z + v.w * v.w;
  }
  for (int off = 32; off; off >>= 1) {
    s  += __shfl_xor(s, off);
    sq += __shfl_xor(sq, off);
  }
  __shared__ float ls[4], lsq[4];
  int wave = t >> 6;
  if ((t & 63) == 0) { ls[wave] = s; lsq[wave] = sq; }
  __syncthreads();
  if (t == 0) {
    float S  = ls[0] + ls[1] + ls[2] + ls[3];
    float SQ = lsq[0] + lsq[1] + lsq[2] + lsq[3];
    float inv = 1.0f / fmaxf(S, 1e-12f);
    stats[2 * b]     = inv;
    stats[2 * b + 1] = SQ * inv * inv;
  }
}

// ---------------------------------------------------------------------------
// Kernel 2: one workgroup per (b,k) row.  SINGLE PASS: the whole row is held
// in registers (64 VGPRs of data).  __launch_bounds__(256, 4) grants a
// 128-VGPR budget (512/4) so the allocator does NOT rematerialize the row
// from memory (R2/R3 showed the default 8-wave/EU target forces VGPR=64 and
// silently converts this to a latency-bound two-pass at ~1 TB/s).
// Candidates {z > zmax-1} are a superset of the sparsemax support
// (tau >= zmax-1 always).  Fast path: wave 0 bitonic-sorts <=64 candidates
// in-register and applies the reference's exact support test.
// Loss = sum p^2 - 2 sum pq + sum q^2 needs only the candidate set.
// ---------------------------------------------------------------------------
__global__ __launch_bounds__(256, 4) void sparsemax_loss_kernel(
    const float* __restrict__ logits, const float* __restrict__ mask,
    const float* __restrict__ stats, float* __restrict__ out) {
  int row = blockIdx.x;        // b*K + k
  int b = row >> 4;            // K == 16
  const float* z = logits + (size_t)row * LL;
  const float* m = mask + (size_t)b * LL;
  const float4* zv = reinterpret_cast<const float4*>(z);
  int t = threadIdx.x;
  int wave = t >> 6, lane = t & 63;

  __shared__ float lds_val[CAP];
  __shared__ int   lds_idx[CAP];
  __shared__ int   lds_n;
  __shared__ float lds_f[4];

  if (t == 0) lds_n = 0;

  // ---- single streaming pass: all 16 loads independent, issued before any
  //      consumption; row stays register-resident through compaction ----
  float4 v[16];
#pragma unroll
  for (int j = 0; j < 16; ++j) v[j] = zv[j * 256 + t];

  float mx0 = -3.0e38f, mx1 = -3.0e38f, mx2 = -3.0e38f, mx3 = -3.0e38f;
#pragma unroll
  for (int j = 0; j < 4; ++j) {
    mx0 = fmaxf(mx0, fmaxf(fmaxf(v[4*j+0].x, v[4*j+0].y), fmaxf(v[4*j+0].z, v[4*j+0].w)));
    mx1 = fmaxf(mx1, fmaxf(fmaxf(v[4*j+1].x, v[4*j+1].y), fmaxf(v[4*j+1].z, v[4*j+1].w)));
    mx2 = fmaxf(mx2, fmaxf(fmaxf(v[4*j+2].x, v[4*j+2].y), fmaxf(v[4*j+2].z, v[4*j+2].w)));
    mx3 = fmaxf(mx3, fmaxf(fmaxf(v[4*j+3].x, v[4*j+3].y), fmaxf(v[4*j+3].z, v[4*j+3].w)));
  }
  float vmax = fmaxf(fmaxf(mx0, mx1), fmaxf(mx2, mx3));
  for (int off = 32; off; off >>= 1) vmax = fmaxf(vmax, __shfl_xor(vmax, off));
  if (lane == 0) lds_f[wave] = vmax;
  __syncthreads();
  float zmax = fmaxf(fmaxf(lds_f[0], lds_f[1]), fmaxf(lds_f[2], lds_f[3]));
  float thr = zmax - 1.0f;

  // ---- candidate compaction straight from registers ----
#pragma unroll
  for (int j = 0; j < 16; ++j) {
    int base = (j * 256 + t) * 4;
    float vv[4] = {v[j].x, v[j].y, v[j].z, v[j].w};
#pragma unroll
    for (int e = 0; e < 4; ++e) {
      if (vv[e] > thr) {
        int pos = atomicAdd(&lds_n, 1);
        if (pos < CAP) { lds_val[pos] = vv[e]; lds_idx[pos] = base + e; }
      }
    }
  }
  __syncthreads();
  int n = lds_n;
  float inv_s = stats[2 * b];
  float sumq2 = stats[2 * b + 1];
  const float scale = 0.5f / (float)(BB * KK);

  if (n <= 64) {
    // ================= fast path: exact sorted solve on wave 0 ============
    if (wave == 0) {
      float c = (lane < n) ? lds_val[lane] : -3.0e38f;
      // bitonic sort, descending across 64 lanes
#pragma unroll
      for (int size = 2; size <= 64; size <<= 1) {
#pragma unroll
        for (int stride = size >> 1; stride > 0; stride >>= 1) {
          float other = __shfl_xor(c, stride);
          bool dirDesc = ((lane & size) == 0);
          bool takeMax = (dirDesc == ((lane & stride) == 0));
          float mn = fminf(c, other), mxv = fmaxf(c, other);
          c = takeMax ? mxv : mn;
        }
      }
      // inclusive prefix sum of sorted values
      float cum = c;
#pragma unroll
      for (int off = 1; off < 64; off <<= 1) {
        float y = __shfl_up(cum, off);
        if (lane >= off) cum += y;
      }
      // reference support test: 1 + k*z_sorted > cumsum
      bool sup = (lane < n) && (1.0f + (float)(lane + 1) * c > cum);
      unsigned long long bal = __ballot(sup);
      int k = __popcll(bal);              // k >= 1 always (top element)
      float S = sup ? c : 0.f;
      for (int off = 32; off; off >>= 1) S += __shfl_xor(S, off);
      float tau = (S - 1.0f) / (float)k;

      // loss over the (unsorted) candidate list; p == 0 outside it
      float a1 = 0.f, a2 = 0.f;
      if (lane < n) {
        float val = lds_val[lane];
        float p = fmaxf(val - tau, 0.f);
        if (p > 0.f) {
          float q = m[lds_idx[lane]] * inv_s;
          a1 = p * p;
          a2 = p * q;
        }
      }
      for (int off = 32; off; off >>= 1) {
        a1 += __shfl_xor(a1, off);
        a2 += __shfl_xor(a2, off);
      }
      if (lane == 0) atomicAdd(out, (a1 - 2.f * a2 + sumq2) * scale);
    }
  } else if (n <= CAP) {
    // ============ mid path: wave-0 bisection over LDS candidates ==========
    if (wave == 0) {
      int nj = (n + 63) >> 6;
      float lo = thr, hi = zmax;
      for (int it = 0; it < 30; ++it) {
        float mid = 0.5f * (lo + hi);
        float s = 0.f;
        for (int j = 0; j < nj; ++j) {
          int i = j * 64 + lane;
          float cc = (i < n) ? lds_val[i] : -3.0e38f;
          s += fmaxf(cc - mid, 0.f);
        }
        for (int off = 32; off; off >>= 1) s += __shfl_xor(s, off);
        if (s >= 1.0f) lo = mid; else hi = mid;
      }
      float S = 0.f, kc = 0.f;
      for (int j = 0; j < nj; ++j) {
        int i = j * 64 + lane;
        float cc = (i < n) ? lds_val[i] : -3.0e38f;
        if (cc > lo) { S += cc; kc += 1.f; }
      }
      for (int off = 32; off; off >>= 1) {
        S  += __shfl_xor(S, off);
        kc += __shfl_xor(kc, off);
      }
      float tau = (S - 1.0f) / kc;

      float a1 = 0.f, a2 = 0.f;
      for (int j = 0; j < nj; ++j) {
        int i = j * 64 + lane;
        if (i < n) {
          float p = fmaxf(lds_val[i] - tau, 0.f);
          if (p > 0.f) {
            float q = m[lds_idx[i]] * inv_s;
            a1 += p * p;
            a2 += p * q;
          }
        }
      }
      for (int off = 32; off; off >>= 1) {
        a1 += __shfl_xor(a1, off);
        a2 += __shfl_xor(a2, off);
      }
      if (lane == 0) atomicAdd(out, (a1 - 2.f * a2 + sumq2) * scale);
    }
  } else {
    // ===== slow path (unreachable for this data): block bisection over
    //       global memory re-reads; correctness only ======================
    __shared__ float red[4], red2[4];
    float lo = thr, hi = zmax;
    for (int it = 0; it < 30; ++it) {
      float mid = 0.5f * (lo + hi);
      float s = 0.f;
      for (int j = 0; j < 16; ++j) {
        float4 vv = zv[j * 256 + t];
        s += fmaxf(vv.x - mid, 0.f) + fmaxf(vv.y - mid, 0.f) +
             fmaxf(vv.z - mid, 0.f) + fmaxf(vv.w - mid, 0.f);
      }
      for (int off = 32; off; off >>= 1) s += __shfl_xor(s, off);
      __syncthreads();
      if (lane == 0) red[wave] = s;
      __syncthreads();
      float tot = red[0] + red[1] + red[2] + red[3];
      if (tot >= 1.0f) lo = mid; else hi = mid;
    }
    float S = 0.f, kc = 0.f;
    for (int j = 0; j < 16; ++j) {
      float4 vv4 = zv[j * 256 + t];
      float vv[4] = {vv4.x, vv4.y, vv4.z, vv4.w};
      for (int e = 0; e < 4; ++e)
        if (vv[e] > lo) { S += vv[e]; kc += 1.f; }
    }
    for (int off = 32; off; off >>= 1) {
      S  += __shfl_xor(S, off);
      kc += __shfl_xor(kc, off);
    }
    __syncthreads();
    if (lane == 0) { red[wave] = S; red2[wave] = kc; }
    __syncthreads();
    S  = red[0] + red[1] + red[2] + red[3];
    kc = red2[0] + red2[1] + red2[2] + red2[3];
    float tau = (S - 1.0f) / kc;

    float a1 = 0.f, a2 = 0.f;
    for (int j = 0; j < 16; ++j) {
      int base = (j * 256 + t) * 4;
      float4 vv4 = zv[j * 256 + t];
      float vv[4] = {vv4.x, vv4.y, vv4.z, vv4.w};
      for (int e = 0; e < 4; ++e) {
        float p = fmaxf(vv[e] - tau, 0.f);
        if (p > 0.f) {
          float q = m[base + e] * inv_s;
          a1 += p * p;
          a2 += p * q;
        }
      }
    }
    for (int off = 32; off; off >>= 1) {
      a1 += __shfl_xor(a1, off);
      a2 += __shfl_xor(a2, off);
    }
    __syncthreads();
    if (lane == 0) { red[wave] = a1; red2[wave] = a2; }
    __syncthreads();
    if (t == 0) {
      a1 = red[0] + red[1] + red[2] + red[3];
      a2 = red2[0] + red2[1] + red2[2] + red2[3];
      atomicAdd(out, (a1 - 2.f * a2 + sumq2) * scale);
    }
  }
}

extern "C" void kernel_launch(void* const* d_in, const int* in_sizes, int n_in,
                              void* d_out, int out_size, void* d_ws, size_t ws_size,
                              hipStream_t stream) {
  const float* logits = (const float*)d_in[0];  // (B,K,L) fp32
  const float* mask   = (const float*)d_in[1];  // (B,L)   fp32
  float* stats = (float*)d_ws;                  // 64 * 2 floats
  float* out   = (float*)d_out;                 // scalar fp32

  hipMemsetAsync(out, 0, sizeof(float), stream);
  mask_stats_kernel<<<BB, 256, 0, stream>>>(mask, stats);
  sparsemax_loss_kernel<<<BB * KK, 256, 0, stream>>>(logits, mask, stats, out);
}